// Round 1
// baseline (18599.959 us; speedup 1.0000x reference)
//
#include <hip/hip_runtime.h>
#include <math.h>

#define TSTEPS 2048
#define BDIM 64
#define HDIM 512

// ---------------- 512x512 transpose: WT[k][o] = W_hh[o][k] ----------------
__global__ __launch_bounds__(256) void transpose512(const float* __restrict__ in,
                                                    float* __restrict__ out) {
  __shared__ float tile[32][33];
  const int bx = blockIdx.x * 32, by = blockIdx.y * 32;
  const int tx = threadIdx.x, ty = threadIdx.y;  // 32 x 8
#pragma unroll
  for (int i = 0; i < 32; i += 8)
    tile[ty + i][tx] = in[(size_t)(by + ty + i) * HDIM + bx + tx];
  __syncthreads();
#pragma unroll
  for (int i = 0; i < 32; i += 8)
    out[(size_t)(bx + ty + i) * HDIM + by + tx] = tile[tx][ty + i];
}

// ---------------- row-block GEMM: C[M][512] = A[M][512] @ B[512][512]^T + bias ----
// 64 rows per WG, full N=512 accumulated in registers before any write, so it is
// safe when C == A (each wave reads only its own rows; writes only in epilogue).
__global__ __launch_bounds__(256) void gemm_rows(
    const float* A, const float* __restrict__ B,
    const float* __restrict__ bias0, const float* __restrict__ bias1,
    float* C) {
  __shared__ float Bt[32][HDIM];  // 64 KiB: Bt[kk][n] for current 32-wide k-chunk
  const int tid = threadIdx.x;
  const int tx = tid & 15;   // n-quad group: n = 4*tx + 64*u
  const int ty = tid >> 4;   // row group: rows 4*ty .. 4*ty+3
  const size_t row0 = (size_t)blockIdx.x * 64;
  const float* a0 = A + (row0 + 4 * ty) * HDIM;

  float4 acc[4][8];
#pragma unroll
  for (int i = 0; i < 4; ++i)
#pragma unroll
    for (int u = 0; u < 8; ++u) acc[i][u] = make_float4(0.f, 0.f, 0.f, 0.f);

  for (int kc = 0; kc < HDIM; kc += 32) {
    // stage Bt[kk][n] = B[n][kc+kk] via 4x4 register-block transpose
#pragma unroll
    for (int rep = 0; rep < 4; ++rep) {
      const int idx = tid + 256 * rep;     // 0..1023
      const int nq = (idx & 127) * 4;      // n base
      const int kq = (idx >> 7) * 4;       // kk base
      float4 r0 = *(const float4*)&B[(size_t)(nq + 0) * HDIM + kc + kq];
      float4 r1 = *(const float4*)&B[(size_t)(nq + 1) * HDIM + kc + kq];
      float4 r2 = *(const float4*)&B[(size_t)(nq + 2) * HDIM + kc + kq];
      float4 r3 = *(const float4*)&B[(size_t)(nq + 3) * HDIM + kc + kq];
      *(float4*)&Bt[kq + 0][nq] = make_float4(r0.x, r1.x, r2.x, r3.x);
      *(float4*)&Bt[kq + 1][nq] = make_float4(r0.y, r1.y, r2.y, r3.y);
      *(float4*)&Bt[kq + 2][nq] = make_float4(r0.z, r1.z, r2.z, r3.z);
      *(float4*)&Bt[kq + 3][nq] = make_float4(r0.w, r1.w, r2.w, r3.w);
    }
    __syncthreads();
    for (int k4 = 0; k4 < 32; k4 += 4) {
      float4 a4[4];
#pragma unroll
      for (int i = 0; i < 4; ++i)
        a4[i] = *(const float4*)&a0[(size_t)i * HDIM + kc + k4];
#pragma unroll
      for (int j = 0; j < 4; ++j) {
        float aj[4];
#pragma unroll
        for (int i = 0; i < 4; ++i) aj[i] = ((const float*)&a4[i])[j];
#pragma unroll
        for (int u = 0; u < 8; ++u) {
          const float4 b4 = *(const float4*)&Bt[k4 + j][4 * tx + 64 * u];
#pragma unroll
          for (int i = 0; i < 4; ++i) {
            acc[i][u].x += aj[i] * b4.x;
            acc[i][u].y += aj[i] * b4.y;
            acc[i][u].z += aj[i] * b4.z;
            acc[i][u].w += aj[i] * b4.w;
          }
        }
      }
    }
    __syncthreads();
  }
  // epilogue: the only writes to C
#pragma unroll
  for (int u = 0; u < 8; ++u) {
    const int n = 4 * tx + 64 * u;
    float4 bv = *(const float4*)&bias0[n];
    if (bias1) {
      const float4 b2 = *(const float4*)&bias1[n];
      bv.x += b2.x; bv.y += b2.y; bv.z += b2.z; bv.w += b2.w;
    }
#pragma unroll
    for (int i = 0; i < 4; ++i) {
      float4 o4 = acc[i][u];
      o4.x += bv.x; o4.y += bv.y; o4.z += bv.z; o4.w += bv.w;
      *(float4*)&C[(row0 + 4 * ty + i) * HDIM + n] = o4;
    }
  }
}

// ---------------- sequential scan: h_t = tanh(xp_t + W_hh h_{t-1}), in place ----
// One WG per batch element (64 WGs, zero inter-WG communication).
// Thread (oq, ks): partial dot over k-slice ks (128 k's) for output quad oq.
__global__ __launch_bounds__(512) void scan_kernel(
    const float* __restrict__ WT,   // [512][512]: WT[k][o] = W_hh[o][k]
    const float* __restrict__ h0p,  // [64][512]
    float* hs) {                    // [2048][64][512]; in: x_proj, out: h (in place)
  const int b = blockIdx.x;
  const int tid = threadIdx.x;
  const int ks = tid >> 7;          // 0..3  (k-slice of 128)
  const int oq = (tid & 127) * 4;   // output quad base
  __shared__ float hsl[4][136];     // h sliced per k-range, padded
  __shared__ float zp[4][HDIM];     // k-slice partial sums
  if (tid < HDIM) hsl[tid >> 7][tid & 127] = h0p[(size_t)b * HDIM + tid];
  __syncthreads();
  const float* wp = WT + (size_t)ks * 128 * HDIM + oq;
  const float* hp = hsl[ks];
  for (int t = 0; t < TSTEPS; ++t) {
    const size_t base = ((size_t)t * BDIM + b) * HDIM;
    float4 xpv = make_float4(0.f, 0.f, 0.f, 0.f);
    if (ks == 0) xpv = *(const float4*)&hs[base + oq];  // prefetch x_proj early
    float4 acc = make_float4(0.f, 0.f, 0.f, 0.f);
#pragma unroll 2
    for (int kc = 0; kc < 128; kc += 16) {
      float4 w[16];
#pragma unroll
      for (int j = 0; j < 16; ++j)
        w[j] = *(const float4*)&wp[(size_t)(kc + j) * HDIM];
      float4 hq[4];
#pragma unroll
      for (int q = 0; q < 4; ++q) hq[q] = *(const float4*)&hp[kc + 4 * q];
#pragma unroll
      for (int j = 0; j < 16; ++j) {
        const float hk = ((const float*)&hq[j >> 2])[j & 3];
        acc.x += w[j].x * hk;
        acc.y += w[j].y * hk;
        acc.z += w[j].z * hk;
        acc.w += w[j].w * hk;
      }
    }
    *(float4*)&zp[ks][oq] = acc;
    __syncthreads();
    if (ks == 0) {  // tid < 128: reduce 4 slices, tanh, publish
      float4 s = xpv;
#pragma unroll
      for (int u = 0; u < 4; ++u) {
        const float4 zv = *(const float4*)&zp[u][oq];
        s.x += zv.x; s.y += zv.y; s.z += zv.z; s.w += zv.w;
      }
      const float4 hv = make_float4(tanhf(s.x), tanhf(s.y), tanhf(s.z), tanhf(s.w));
      *(float4*)&hs[base + oq] = hv;                 // h_all for output GEMM
      *(float4*)&hsl[oq >> 7][oq & 127] = hv;        // h for next step
    }
    __syncthreads();
  }
}

extern "C" void kernel_launch(void* const* d_in, const int* in_sizes, int n_in,
                              void* d_out, int out_size, void* d_ws, size_t ws_size,
                              hipStream_t stream) {
  const float* x     = (const float*)d_in[0];
  const float* h0    = (const float*)d_in[1];
  const float* W_ih  = (const float*)d_in[2];
  const float* b_ih  = (const float*)d_in[3];
  const float* W_hh  = (const float*)d_in[4];
  const float* b_hh  = (const float*)d_in[5];
  const float* W_out = (const float*)d_in[6];
  const float* b_out = (const float*)d_in[7];
  float* out = (float*)d_out;
  float* WT  = (float*)d_ws;  // 512*512 floats = 1 MiB (assumes ws_size >= 1 MiB)

  // 1. W_hh^T for coalesced scan reads
  transpose512<<<dim3(16, 16), dim3(32, 8), 0, stream>>>(W_hh, WT);
  // 2. x_proj = x @ W_ih^T + b_ih + b_hh  -> d_out (scratch use of output buffer)
  gemm_rows<<<TSTEPS * BDIM / 64, 256, 0, stream>>>(x, W_ih, b_ih, b_hh, out);
  // 3. sequential recurrence, in place on d_out
  scan_kernel<<<BDIM, 512, 0, stream>>>(WT, h0, out);
  // 4. y = h_all @ W_out^T + b_out, in place on d_out (row-exclusive per WG)
  gemm_rows<<<TSTEPS * BDIM / 64, 256, 0, stream>>>(out, W_out, b_out, nullptr, out);
}